// Round 9
// baseline (30.241 us; speedup 1.0000x reference)
//
#include <hip/hip_runtime.h>

// 3D median filter 3x3x3, stride 1, reflect padding.
// x: (2, 1, 160, 160, 160) fp32 -> same shape. Median = rank 13 (0-based) of 27.
// Round 8: R7's fence-pinned depth-1 prefetch pipeline + CH=4 for 2x waves
// (8000 waves = 7.8/SIMD). TLP x pinned-ILP together: R4 had TLP w/o pinning,
// R7 had pinning w/o TLP; both stalled ~28 us. 4-wide hf4 packed-f16 network.

typedef __fp16 hf2 __attribute__((ext_vector_type(2)));
typedef __fp16 hf4 __attribute__((ext_vector_type(4)));

#define DEV __device__ __forceinline__
#define SCHED_FENCE() __builtin_amdgcn_sched_barrier(0)

DEV hf4 hmin4(hf4 a, hf4 b) { return __builtin_elementwise_min(a, b); }
DEV hf4 hmax4(hf4 a, hf4 b) { return __builtin_elementwise_max(a, b); }
DEV void ce(hf4& a, hf4& b) { hf4 lo = hmin4(a, b); hf4 hi = hmax4(a, b); a = lo; b = hi; }
DEV hf2 pk2(float a, float b) { return __builtin_amdgcn_cvt_pkrtz(a, b); }
DEV hf4 cat(hf2 a, hf2 b) { return __builtin_shufflevector(a, b, 0, 1, 2, 3); }

DEV void sort3(hf4& a, hf4& b, hf4& c) { ce(a, b); ce(a, c); ce(b, c); }

// Batcher odd-even merges of small sorted sequences (verified exact, rounds 1-7).
DEV void merge21(hf4 a0, hf4 a1, hf4 b0, hf4 z[3]) {
    hf4 e0 = a0, e1 = b0; ce(e0, e1);
    z[0] = e0; z[1] = a1; z[2] = e1; ce(z[1], z[2]);
}
DEV void merge22(hf4 a0, hf4 a1, hf4 b0, hf4 b1, hf4 z[4]) {
    hf4 p0 = a0, p1 = b0; ce(p0, p1);
    hf4 q0 = a1, q1 = b1; ce(q0, q1);
    z[0] = p0; z[1] = q0; z[2] = p1; ce(z[1], z[2]); z[3] = q1;
}
DEV void merge31(hf4 a0, hf4 a1, hf4 a2, hf4 b0, hf4 z[4]) {
    hf4 e[3]; merge21(a0, a2, b0, e);
    z[0] = e[0]; z[1] = a1; z[2] = e[1]; ce(z[1], z[2]); z[3] = e[2];
}
DEV void merge32(hf4 a0, hf4 a1, hf4 a2, hf4 b0, hf4 b1, hf4 z[5]) {
    hf4 e[3]; merge21(a0, a2, b0, e);
    hf4 o0 = a1, o1 = b1; ce(o0, o1);
    z[0] = e[0];
    z[1] = o0; z[2] = e[1]; ce(z[1], z[2]);
    z[3] = o1; z[4] = e[2]; ce(z[3], z[4]);
}
DEV void merge33(const hf4 a[3], const hf4 b[3], hf4 z[6]) {
    hf4 e[4]; merge22(a[0], a[2], b[0], b[2], e);
    hf4 o0 = a[1], o1 = b[1]; ce(o0, o1);
    z[0] = e[0];
    z[1] = o0; z[2] = e[1]; ce(z[1], z[2]);
    z[3] = o1; z[4] = e[2]; ce(z[3], z[4]);
    z[5] = e[3];
}
DEV void merge63(const hf4 a[6], const hf4 b[3], hf4 z[9]) {
    hf4 e[5]; merge32(a[0], a[2], a[4], b[0], b[2], e);
    hf4 o[4]; merge31(a[1], a[3], a[5], b[1], o);
    z[0] = e[0];
    z[1] = o[0]; z[2] = e[1]; ce(z[1], z[2]);
    z[3] = o[1]; z[4] = e[2]; ce(z[3], z[4]);
    z[5] = o[2]; z[6] = e[3]; ce(z[5], z[6]);
    z[7] = o[3]; z[8] = e[4]; ce(z[7], z[8]);
}
DEV void merge44(const hf4 a[4], const hf4 b[4], hf4 z[8]) {
    hf4 e[4]; merge22(a[0], a[2], b[0], b[2], e);
    hf4 o[4]; merge22(a[1], a[3], b[1], b[3], o);
    z[0] = e[0];
    z[1] = o[0]; z[2] = e[1]; ce(z[1], z[2]);
    z[3] = o[1]; z[4] = e[2]; ce(z[3], z[4]);
    z[5] = o[2]; z[6] = e[3]; ce(z[5], z[6]);
    z[7] = o[3];
}
DEV void merge55(const hf4 a[5], const hf4 b[5], hf4 z[10]) {
    hf4 ae[3] = {a[0], a[2], a[4]}, be[3] = {b[0], b[2], b[4]};
    hf4 e[6]; merge33(ae, be, e);
    hf4 o[4]; merge22(a[1], a[3], b[1], b[3], o);
    z[0] = e[0];
    z[1] = o[0]; z[2] = e[1]; ce(z[1], z[2]);
    z[3] = o[1]; z[4] = e[2]; ce(z[3], z[4]);
    z[5] = o[2]; z[6] = e[3]; ce(z[5], z[6]);
    z[7] = o[3]; z[8] = e[4]; ce(z[7], z[8]);
    z[9] = e[5];
}
DEV void merge99(const hf4 a[9], const hf4 b[9], hf4 z[18]) {
    hf4 ae[5] = {a[0], a[2], a[4], a[6], a[8]};
    hf4 be[5] = {b[0], b[2], b[4], b[6], b[8]};
    hf4 e[10]; merge55(ae, be, e);
    hf4 ao[4] = {a[1], a[3], a[5], a[7]};
    hf4 bo[4] = {b[1], b[3], b[5], b[7]};
    hf4 o[8]; merge44(ao, bo, o);
    z[0] = e[0];
#pragma unroll
    for (int i = 0; i < 8; i++) {
        z[2 * i + 1] = o[i];
        z[2 * i + 2] = e[i + 1];
        ce(z[2 * i + 1], z[2 * i + 2]);
    }
    z[17] = e[9];
}

// Raw taps (6 per row: L, c0..c3, R) of the 3x3x(4-wide) window -> 18 floats.
DEV void load18(const float* __restrict__ pb, const int ro[3], int cL, int x0, int cR,
                float R[18]) {
#pragma unroll
    for (int i = 0; i < 3; i++) {
        const float* p = pb + ro[i];
        R[i * 6 + 0] = p[cL];
        float4 v = *reinterpret_cast<const float4*>(p + x0);  // 16B-aligned
        R[i * 6 + 1] = v.x; R[i * 6 + 2] = v.y;
        R[i * 6 + 3] = v.z; R[i * 6 + 4] = v.w;
        R[i * 6 + 5] = p[cR];
    }
}

// 18 raw floats -> packed rows -> sorted-9 (4-wide packed).
DEV void sortp(const float R[18], hf4 M[9]) {
    hf4 r[3][3];
#pragma unroll
    for (int i = 0; i < 3; i++) {
        const float* q = R + i * 6;
        hf2 pAL = pk2(q[0], q[1]);
        hf2 pAC = pk2(q[1], q[2]);
        hf2 pSH = pk2(q[2], q[3]);   // right-taps of pair A == left-taps of pair B
        hf2 pBC = pk2(q[3], q[4]);
        hf2 pBR = pk2(q[4], q[5]);
        r[i][0] = cat(pAL, pSH);
        r[i][1] = cat(pAC, pBC);
        r[i][2] = cat(pSH, pBR);
        sort3(r[i][0], r[i][1], r[i][2]);
    }
    hf4 s6[6]; merge33(r[0], r[1], s6);
    merge63(s6, r[2], M);
}

// rank-13-of-27 from merged-18 E and sorted-9 R:
//   med = min(E[13], min_i max(R[i], E[12-i]))   (verified exact in round 1)
DEV hf4 sel13(const hf4 E[18], const hf4 R[9]) {
    hf4 m = E[13];
#pragma unroll
    for (int i = 0; i < 9; i++) m = hmin4(m, hmax4(R[i], E[12 - i]));
    return m;
}

constexpr int Bb = 2, Dd = 160, Hh = 160, Ww = 160;
constexpr int HW = Hh * Ww;            // 25600
constexpr int WQ = Ww / 4;             // 40 x-quads per row
constexpr int CH = 4;                  // z-chunk per thread (even)
constexpr int NCH = Dd / CH;           // 40
constexpr int TOTAL = Bb * NCH * Hh * WQ;  // 512,000 threads = 8000 waves

__global__ __launch_bounds__(256, 2) void MedianPool3d_68994354642979_kernel(
    const float* __restrict__ in, float* __restrict__ out) {
    int tid = blockIdx.x * 256 + threadIdx.x;
    int q = tid % WQ;
    int rest = tid / WQ;
    int y = rest % Hh;
    rest /= Hh;
    int chunk = rest % NCH;
    int b = rest / NCH;
    int x0 = q * 4;

    // reflect padding (jnp.pad mode="reflect", pad=1)
    int ym = (y == 0) ? 1 : y - 1;
    int yp = (y == Hh - 1) ? Hh - 2 : y + 1;
    int ro[3] = {ym * Ww, y * Ww, yp * Ww};
    int cL = (x0 == 0) ? 1 : x0 - 1;                 // left tap of col x0
    int cR = (x0 + 4 == Ww) ? (Ww - 2) : x0 + 4;     // right tap of col x0+3

    const float* base = in + (size_t)b * Dd * HW;
    float* ob = out + (size_t)b * Dd * HW;
    int z0 = chunk * CH;

    auto planeptr = [&](int p) {
        if (p < 0) p = -p;                 // reflect(-1) = 1
        if (p >= Dd) p = 2 * Dd - 2 - p;   // reflect(160) = 158
        return base + (size_t)p * HW;
    };

    // 4-slot ring of sorted planes: plane (z0-1)+m -> slot m&3.
    hf4 SS[4][9];
    // Raw prefetch buffers: RT0 even-rel planes, RT1 odd-rel planes.
    float RT0[18], RT1[18];

    {   // prologue: issue rel -1,0,1,2 together; sort -1,0,1; issue rel 3.
        float P0[18], P1[18];
        load18(planeptr(z0 - 1), ro, cL, x0, cR, P0);
        load18(planeptr(z0),     ro, cL, x0, cR, P1);
        load18(planeptr(z0 + 1), ro, cL, x0, cR, RT1);
        load18(planeptr(z0 + 2), ro, cL, x0, cR, RT0);
        SCHED_FENCE();
        sortp(P0, SS[0]);   // S[z0-1]
        sortp(P1, SS[1]);   // S[z0]
        sortp(RT1, SS[2]);  // S[z0+1]
        load18(planeptr(z0 + 3), ro, cL, x0, cR, RT1);
        SCHED_FENCE();
    }

#pragma unroll
    for (int j = 0; j < CH / 2; j++) {
        const int z = z0 + 2 * j;
        const int sA = (2 * j) & 3;      // S[z-1]
        const int sB = (2 * j + 1) & 3;  // S[z]
        const int sC = (2 * j + 2) & 3;  // S[z+1]
        const int sD = (2 * j + 3) & 3;  // S[z+2]

        // consume RT0 (plane z+2, loaded a full iteration ago)
        sortp(RT0, SS[sD]);
        if (j < CH / 2 - 1)  // prefetch plane z+4 into RT0; pinned by the fence
            load18(planeptr(z + 4), ro, cL, x0, cR, RT0);
        SCHED_FENCE();

        hf4 E[18];
        merge99(SS[sB], SS[sC], E);      // shared pair (z, z+1) -> used twice
        hf4 m0 = sel13(E, SS[sA]);       // output z   : third plane z-1
        hf4 m1 = sel13(E, SS[sD]);       // output z+1 : third plane z+2

        float* o0 = ob + (size_t)z * HW + ro[1] + x0;   // 16B-aligned
        float* o1 = o0 + HW;
        *reinterpret_cast<float4*>(o0) =
            make_float4((float)m0.x, (float)m0.y, (float)m0.z, (float)m0.w);
        *reinterpret_cast<float4*>(o1) =
            make_float4((float)m1.x, (float)m1.y, (float)m1.z, (float)m1.w);

        if (j < CH / 2 - 1) {  // consume RT1 (plane z+3) into the retired slot
            sortp(RT1, SS[sA]);
            if (j < CH / 2 - 2)  // prefetch plane z+5 into RT1
                load18(planeptr(z + 5), ro, cL, x0, cR, RT1);
        }
        SCHED_FENCE();
    }
}

extern "C" void kernel_launch(void* const* d_in, const int* in_sizes, int n_in,
                              void* d_out, int out_size, void* d_ws, size_t ws_size,
                              hipStream_t stream) {
    const float* x = (const float*)d_in[0];
    float* out = (float*)d_out;
    constexpr int threads = 256;
    constexpr int blocks = TOTAL / threads;  // 2000 exactly
    MedianPool3d_68994354642979_kernel<<<blocks, threads, 0, stream>>>(x, out);
}